// Round 1
// baseline (2047.578 us; speedup 1.0000x reference)
//
#include <hip/hip_runtime.h>

// ---------------------------------------------------------------------------
// SAGE_DGL: 2-layer GraphSAGE (mean agg) forward on MI355X.
// Pipeline: memset accumulators -> scatter-add (atomics) -> fused GEMM1
// (self+neigh concat-K, mean fold, bias, relu) -> scatter-add -> GEMM2 ->
// in-place log_softmax on d_out.
// ---------------------------------------------------------------------------

constexpr int D_IN  = 128;
constexpr int HID   = 256;
constexpr int OUT_D = 64;
constexpr int SIZE1 = 25000;
constexpr int SIZE2 = 5000;

// ---------------------------------------------------------------------------
// Scatter-add aggregation: one thread per (edge, 4-col group).
// DV = D/4 (compile-time so the div/mod become shifts).
// ---------------------------------------------------------------------------
template <int DV>
__global__ void scatter_add_kernel(const float* __restrict__ X,
                                   const int* __restrict__ src,
                                   const int* __restrict__ dst,
                                   float* __restrict__ agg,
                                   float* __restrict__ deg,
                                   int E) {
    long i = (long)blockIdx.x * blockDim.x + threadIdx.x;
    long total = (long)E * DV;
    if (i >= total) return;
    int e = (int)(i / DV);
    int c = (int)(i - (long)e * DV);
    int s = src[e];
    int d = dst[e];
    const float4 v = reinterpret_cast<const float4*>(X)[(long)s * DV + c];
    float* out = agg + (long)d * (DV * 4) + c * 4;
    unsafeAtomicAdd(out + 0, v.x);
    unsafeAtomicAdd(out + 1, v.y);
    unsafeAtomicAdd(out + 2, v.z);
    unsafeAtomicAdd(out + 3, v.w);
    if (c == 0) unsafeAtomicAdd(&deg[d], 1.0f);
}

// ---------------------------------------------------------------------------
// Fused SAGE GEMM:  C[i,j] = act( Aself[i,:]@Bself[:,j]
//                               + (Aagg[i,:]/max(deg[i],1))@Bneigh[:,j]
//                               + bias[j] )
// Aself/Aagg: [M,K] row-major. Bself/Bneigh: [K,N] row-major.
// Tiled fp32: BMxBN tile, 256 threads, TMxTN micro-tile per thread.
// ---------------------------------------------------------------------------
template <int BM, int BN, int BK, int TM, int TN, bool RELU>
__global__ void sage_gemm(const float* __restrict__ Aself,
                          const float* __restrict__ Aagg,
                          const float* __restrict__ deg,
                          const float* __restrict__ Bself,
                          const float* __restrict__ Bneigh,
                          const float* __restrict__ bias,
                          float* __restrict__ C,
                          int M, int N, int K) {
    static_assert((BM / TM) * (BN / TN) == 256, "256 threads");
    constexpr int LA = BM * BK / 256;   // A elems per thread per tile
    constexpr int LB = BK * BN / 256;   // B elems per thread per tile
    constexpr int PAD = 4;              // keep 16B alignment of As rows

    __shared__ float As[BK][BM + PAD];
    __shared__ float Bs[BK][BN];

    const int tid = threadIdx.x;
    const int tx = tid % (BN / TN);
    const int ty = tid / (BN / TN);
    const int rowBase = blockIdx.x * BM;
    const int colBase = blockIdx.y * BN;

    float acc[TM][TN];
#pragma unroll
    for (int a = 0; a < TM; ++a)
#pragma unroll
        for (int b = 0; b < TN; ++b) acc[a][b] = 0.0f;

#pragma unroll
    for (int p = 0; p < 2; ++p) {
        const float* __restrict__ A = p ? Aagg : Aself;
        const float* __restrict__ B = p ? Bneigh : Bself;
        for (int k0 = 0; k0 < K; k0 += BK) {
            __syncthreads();
            // load A tile (transposed into LDS), fold mean-divide when p==1
#pragma unroll
            for (int i = 0; i < LA; ++i) {
                int f = i * 256 + tid;
                int r = f / BK;
                int k = f % BK;
                int gr = rowBase + r;
                int grc = gr < M ? gr : M - 1;
                float v = A[(long)grc * K + k0 + k];
                if (p) v *= 1.0f / fmaxf(deg[grc], 1.0f);
                As[k][r] = v;
            }
            // load B tile
#pragma unroll
            for (int i = 0; i < LB; ++i) {
                int f = i * 256 + tid;
                int kk = f / BN;
                int c = f % BN;
                Bs[kk][c] = B[(long)(k0 + kk) * N + colBase + c];
            }
            __syncthreads();
#pragma unroll
            for (int k = 0; k < BK; ++k) {
                float a[TM], b[TN];
#pragma unroll
                for (int t = 0; t < TM; ++t) a[t] = As[k][ty * TM + t];
#pragma unroll
                for (int t = 0; t < TN; ++t) b[t] = Bs[k][tx * TN + t];
#pragma unroll
                for (int t = 0; t < TM; ++t)
#pragma unroll
                    for (int u = 0; u < TN; ++u) acc[t][u] += a[t] * b[u];
            }
        }
    }

    // epilogue
#pragma unroll
    for (int t = 0; t < TM; ++t) {
        int gr = rowBase + ty * TM + t;
        if (gr >= M) continue;
#pragma unroll
        for (int u = 0; u < TN; ++u) {
            int gc = colBase + tx * TN + u;
            float v = acc[t][u] + bias[gc];
            if (RELU) v = fmaxf(v, 0.0f);
            C[(long)gr * N + gc] = v;
        }
    }
}

// ---------------------------------------------------------------------------
// In-place log_softmax over rows of 64. One wave (64 lanes) per row.
// ---------------------------------------------------------------------------
__global__ void log_softmax_kernel(float* __restrict__ C, int M) {
    int row = blockIdx.x * 4 + (threadIdx.x >> 6);
    int lane = threadIdx.x & 63;
    if (row >= M) return;
    float v = C[(long)row * OUT_D + lane];
    float m = v;
#pragma unroll
    for (int o = 32; o; o >>= 1) m = fmaxf(m, __shfl_xor(m, o));
    float ex = __expf(v - m);
    float s = ex;
#pragma unroll
    for (int o = 32; o; o >>= 1) s += __shfl_xor(s, o);
    C[(long)row * OUT_D + lane] = v - m - __logf(s);
}

// ---------------------------------------------------------------------------

extern "C" void kernel_launch(void* const* d_in, const int* in_sizes, int n_in,
                              void* d_out, int out_size, void* d_ws, size_t ws_size,
                              hipStream_t stream) {
    const float* x       = (const float*)d_in[0];
    const float* Wself1  = (const float*)d_in[1];
    const float* Wneigh1 = (const float*)d_in[2];
    const float* b1      = (const float*)d_in[3];
    const float* Wself2  = (const float*)d_in[4];
    const float* Wneigh2 = (const float*)d_in[5];
    const float* b2      = (const float*)d_in[6];
    const int* es1 = (const int*)d_in[7];
    const int* ed1 = (const int*)d_in[8];
    const int* es2 = (const int*)d_in[9];
    const int* ed2 = (const int*)d_in[10];
    const int E1 = in_sizes[7];
    const int E2 = in_sizes[9];

    // workspace layout (fp32):
    // [agg1: SIZE1*128][deg1: SIZE1][agg2: SIZE2*256][deg2: SIZE2][h1: SIZE1*256]
    float* agg1 = (float*)d_ws;
    float* deg1 = agg1 + (long)SIZE1 * D_IN;
    float* agg2 = deg1 + SIZE1;
    float* deg2 = agg2 + (long)SIZE2 * HID;
    float* h1   = deg2 + SIZE2;
    const size_t zero_elems =
        (size_t)SIZE1 * D_IN + SIZE1 + (size_t)SIZE2 * HID + SIZE2;
    hipMemsetAsync(d_ws, 0, zero_elems * sizeof(float), stream);

    // ---- layer 1 aggregation: sum x[src] into agg1[dst], count deg1
    {
        long total = (long)E1 * (D_IN / 4);
        int grid = (int)((total + 255) / 256);
        scatter_add_kernel<D_IN / 4><<<grid, 256, 0, stream>>>(
            x, es1, ed1, agg1, deg1, E1);
    }
    // ---- layer 1 GEMM: h1 = relu(x[:S1]@Wself1 + mean1@Wneigh1 + b1)
    {
        dim3 grid((SIZE1 + 63) / 64, HID / 64);
        sage_gemm<64, 64, 16, 4, 4, true><<<grid, 256, 0, stream>>>(
            x, agg1, deg1, Wself1, Wneigh1, b1, h1, SIZE1, HID, D_IN);
    }
    // ---- layer 2 aggregation: sum h1[src] into agg2[dst], count deg2
    {
        long total = (long)E2 * (HID / 4);
        int grid = (int)((total + 255) / 256);
        scatter_add_kernel<HID / 4><<<grid, 256, 0, stream>>>(
            h1, es2, ed2, agg2, deg2, E2);
    }
    // ---- layer 2 GEMM: logits = h1[:S2]@Wself2 + mean2@Wneigh2 + b2
    {
        dim3 grid((SIZE2 + 63) / 64, OUT_D / 32);
        sage_gemm<64, 32, 16, 4, 2, false><<<grid, 256, 0, stream>>>(
            h1, agg2, deg2, Wself2, Wneigh2, b2, (float*)d_out, SIZE2, OUT_D, HID);
    }
    // ---- log_softmax in place on d_out
    {
        int grid = (SIZE2 + 3) / 4;
        log_softmax_kernel<<<grid, 256, 0, stream>>>((float*)d_out, SIZE2);
    }
}

// Round 2
// 330.418 us; speedup vs baseline: 6.1969x; 6.1969x over previous
//
#include <hip/hip_runtime.h>

// ---------------------------------------------------------------------------
// SAGE_DGL: 2-layer GraphSAGE (mean agg) forward on MI355X.
// Round 2: replace scatter-atomics with device-built CSR + pull aggregation.
// Pipeline per layer: histogram(dst) -> exclusive scan -> CSR fill ->
// pull-mean -> fused GEMM. Then log_softmax in place on d_out.
// ---------------------------------------------------------------------------

constexpr int D_IN  = 128;
constexpr int HID   = 256;
constexpr int OUT_D = 64;
constexpr int SIZE1 = 25000;
constexpr int SIZE2 = 5000;

// ---------------------------------------------------------------------------
// CSR build step 1: histogram of dst
// ---------------------------------------------------------------------------
__global__ void hist_kernel(const int* __restrict__ dst, int* __restrict__ counts,
                            int E) {
    int e = blockIdx.x * blockDim.x + threadIdx.x;
    if (e < E) atomicAdd(&counts[dst[e]], 1);
}

// ---------------------------------------------------------------------------
// CSR build step 2: exclusive scan (single block, 1024 threads, n <= 25600)
// offsets[0..n] written (offsets[n] = total).
// ---------------------------------------------------------------------------
__global__ void scan_kernel(const int* __restrict__ counts,
                            int* __restrict__ offsets, int n) {
    __shared__ int part[1024];
    const int tid = threadIdx.x;
    const int chunk = (n + 1023) / 1024;
    const int beg = tid * chunk;
    int sum = 0;
    for (int i = 0; i < chunk; ++i) {
        int idx = beg + i;
        if (idx < n) sum += counts[idx];
    }
    const int own = sum;
    part[tid] = sum;
    __syncthreads();
    for (int off = 1; off < 1024; off <<= 1) {
        int v = (tid >= off) ? part[tid - off] : 0;
        __syncthreads();
        part[tid] += v;
        __syncthreads();
    }
    if (tid == 0) offsets[n] = part[1023];
    int run = part[tid] - own;  // exclusive prefix
    for (int i = 0; i < chunk; ++i) {
        int idx = beg + i;
        if (idx < n) {
            offsets[idx] = run;
            run += counts[idx];
        }
    }
}

// ---------------------------------------------------------------------------
// CSR build step 3: fill src indices into dst-sorted slots
// ---------------------------------------------------------------------------
__global__ void fill_kernel(const int* __restrict__ src, const int* __restrict__ dst,
                            const int* __restrict__ offsets, int* __restrict__ cursor,
                            int* __restrict__ csr, int E) {
    int e = blockIdx.x * blockDim.x + threadIdx.x;
    if (e >= E) return;
    int d = dst[e];
    int pos = offsets[d] + atomicAdd(&cursor[d], 1);
    csr[pos] = src[e];
}

// ---------------------------------------------------------------------------
// Pull-mode mean aggregation: one block of D threads per dst node.
// csr[e] is block-uniform (scalarizes); X row reads are coalesced.
// Writes mean directly (divide folded in).
// ---------------------------------------------------------------------------
template <int D>
__global__ void agg_pull_kernel(const float* __restrict__ X,
                                const int* __restrict__ csr,
                                const int* __restrict__ offsets,
                                float* __restrict__ mean) {
    const int d = blockIdx.x;
    const int tid = threadIdx.x;
    const int beg = offsets[d];
    const int end = offsets[d + 1];
    float acc0 = 0.0f, acc1 = 0.0f;
    int e = beg;
    for (; e + 1 < end; e += 2) {
        int s0 = csr[e];
        int s1 = csr[e + 1];
        acc0 += X[(long)s0 * D + tid];
        acc1 += X[(long)s1 * D + tid];
    }
    if (e < end) acc0 += X[(long)csr[e] * D + tid];
    float inv = 1.0f / (float)max(end - beg, 1);
    mean[(long)d * D + tid] = (acc0 + acc1) * inv;
}

// ---------------------------------------------------------------------------
// Fused SAGE GEMM:  C[i,j] = act( Aself[i,:]@Bself[:,j] + Amean[i,:]@Bneigh[:,j]
//                               + bias[j] )
// ---------------------------------------------------------------------------
template <int BM, int BN, int BK, int TM, int TN, bool RELU>
__global__ void sage_gemm(const float* __restrict__ Aself,
                          const float* __restrict__ Amean,
                          const float* __restrict__ Bself,
                          const float* __restrict__ Bneigh,
                          const float* __restrict__ bias,
                          float* __restrict__ C,
                          int M, int N, int K) {
    static_assert((BM / TM) * (BN / TN) == 256, "256 threads");
    constexpr int LA = BM * BK / 256;
    constexpr int LB = BK * BN / 256;
    constexpr int PAD = 4;

    __shared__ float As[BK][BM + PAD];
    __shared__ float Bs[BK][BN];

    const int tid = threadIdx.x;
    const int tx = tid % (BN / TN);
    const int ty = tid / (BN / TN);
    const int rowBase = blockIdx.x * BM;
    const int colBase = blockIdx.y * BN;

    float acc[TM][TN];
#pragma unroll
    for (int a = 0; a < TM; ++a)
#pragma unroll
        for (int b = 0; b < TN; ++b) acc[a][b] = 0.0f;

#pragma unroll
    for (int p = 0; p < 2; ++p) {
        const float* __restrict__ A = p ? Amean : Aself;
        const float* __restrict__ B = p ? Bneigh : Bself;
        for (int k0 = 0; k0 < K; k0 += BK) {
            __syncthreads();
#pragma unroll
            for (int i = 0; i < LA; ++i) {
                int f = i * 256 + tid;
                int r = f / BK;
                int k = f % BK;
                int gr = rowBase + r;
                int grc = gr < M ? gr : M - 1;
                As[k][r] = A[(long)grc * K + k0 + k];
            }
#pragma unroll
            for (int i = 0; i < LB; ++i) {
                int f = i * 256 + tid;
                int kk = f / BN;
                int c = f % BN;
                Bs[kk][c] = B[(long)(k0 + kk) * N + colBase + c];
            }
            __syncthreads();
#pragma unroll
            for (int k = 0; k < BK; ++k) {
                float a[TM], b[TN];
#pragma unroll
                for (int t = 0; t < TM; ++t) a[t] = As[k][ty * TM + t];
#pragma unroll
                for (int t = 0; t < TN; ++t) b[t] = Bs[k][tx * TN + t];
#pragma unroll
                for (int t = 0; t < TM; ++t)
#pragma unroll
                    for (int u = 0; u < TN; ++u) acc[t][u] += a[t] * b[u];
            }
        }
    }

#pragma unroll
    for (int t = 0; t < TM; ++t) {
        int gr = rowBase + ty * TM + t;
        if (gr >= M) continue;
#pragma unroll
        for (int u = 0; u < TN; ++u) {
            int gc = colBase + tx * TN + u;
            float v = acc[t][u] + bias[gc];
            if (RELU) v = fmaxf(v, 0.0f);
            C[(long)gr * N + gc] = v;
        }
    }
}

// ---------------------------------------------------------------------------
// In-place log_softmax over rows of 64. One wave per row.
// ---------------------------------------------------------------------------
__global__ void log_softmax_kernel(float* __restrict__ C, int M) {
    int row = blockIdx.x * 4 + (threadIdx.x >> 6);
    int lane = threadIdx.x & 63;
    if (row >= M) return;
    float v = C[(long)row * OUT_D + lane];
    float m = v;
#pragma unroll
    for (int o = 32; o; o >>= 1) m = fmaxf(m, __shfl_xor(m, o));
    float ex = __expf(v - m);
    float s = ex;
#pragma unroll
    for (int o = 32; o; o >>= 1) s += __shfl_xor(s, o);
    C[(long)row * OUT_D + lane] = v - m - __logf(s);
}

// ---------------------------------------------------------------------------

extern "C" void kernel_launch(void* const* d_in, const int* in_sizes, int n_in,
                              void* d_out, int out_size, void* d_ws, size_t ws_size,
                              hipStream_t stream) {
    const float* x       = (const float*)d_in[0];
    const float* Wself1  = (const float*)d_in[1];
    const float* Wneigh1 = (const float*)d_in[2];
    const float* b1      = (const float*)d_in[3];
    const float* Wself2  = (const float*)d_in[4];
    const float* Wneigh2 = (const float*)d_in[5];
    const float* b2      = (const float*)d_in[6];
    const int* es1 = (const int*)d_in[7];
    const int* ed1 = (const int*)d_in[8];
    const int* es2 = (const int*)d_in[9];
    const int* ed2 = (const int*)d_in[10];
    const int E1 = in_sizes[7];
    const int E2 = in_sizes[9];

    // ---- workspace layout ----
    // ints: [counts1|cursor1|counts2|cursor2] (zeroed together)
    //       [offsets1][offsets2][csr1][csr2]
    // floats: [mean1][mean2][h1]
    int* counts1  = (int*)d_ws;
    int* cursor1  = counts1 + SIZE1;
    int* counts2  = cursor1 + SIZE1;
    int* cursor2  = counts2 + SIZE2;
    int* offsets1 = cursor2 + SIZE2;                 // SIZE1+1
    int* offsets2 = offsets1 + SIZE1 + 1;            // SIZE2+1
    int* csr1     = offsets2 + SIZE2 + 1;
    int* csr2     = csr1 + E1;
    float* mean1  = (float*)(csr2 + E2);
    float* mean2  = mean1 + (long)SIZE1 * D_IN;
    float* h1     = mean2 + (long)SIZE2 * HID;

    hipMemsetAsync(d_ws, 0, (2 * SIZE1 + 2 * SIZE2) * sizeof(int), stream);

    // ---- layer 1 CSR build + pull-mean ----
    hist_kernel<<<(E1 + 255) / 256, 256, 0, stream>>>(ed1, counts1, E1);
    scan_kernel<<<1, 1024, 0, stream>>>(counts1, offsets1, SIZE1);
    fill_kernel<<<(E1 + 255) / 256, 256, 0, stream>>>(es1, ed1, offsets1, cursor1,
                                                      csr1, E1);
    agg_pull_kernel<D_IN><<<SIZE1, D_IN, 0, stream>>>(x, csr1, offsets1, mean1);

    // ---- layer 1 GEMM: h1 = relu(x[:S1]@Wself1 + mean1@Wneigh1 + b1)
    {
        dim3 grid((SIZE1 + 63) / 64, HID / 64);
        sage_gemm<64, 64, 16, 4, 4, true><<<grid, 256, 0, stream>>>(
            x, mean1, Wself1, Wneigh1, b1, h1, SIZE1, HID, D_IN);
    }

    // ---- layer 2 CSR build + pull-mean ----
    hist_kernel<<<(E2 + 255) / 256, 256, 0, stream>>>(ed2, counts2, E2);
    scan_kernel<<<1, 1024, 0, stream>>>(counts2, offsets2, SIZE2);
    fill_kernel<<<(E2 + 255) / 256, 256, 0, stream>>>(es2, ed2, offsets2, cursor2,
                                                      csr2, E2);
    agg_pull_kernel<HID><<<SIZE2, HID, 0, stream>>>(h1, csr2, offsets2, mean2);

    // ---- layer 2 GEMM: logits = h1[:S2]@Wself2 + mean2@Wneigh2 + b2
    {
        dim3 grid((SIZE2 + 63) / 64, OUT_D / 32);
        sage_gemm<64, 32, 16, 4, 2, false><<<grid, 256, 0, stream>>>(
            h1, mean2, Wself2, Wneigh2, b2, (float*)d_out, SIZE2, OUT_D, HID);
    }

    // ---- log_softmax in place on d_out
    log_softmax_kernel<<<(SIZE2 + 3) / 4, 256, 0, stream>>>((float*)d_out, SIZE2);
}

// Round 3
// 273.998 us; speedup vs baseline: 7.4730x; 1.2059x over previous
//
#include <hip/hip_runtime.h>

// ---------------------------------------------------------------------------
// SAGE_DGL: 2-layer GraphSAGE (mean agg) forward on MI355X.
// Round 3: bf16 everywhere on the heavy paths.
//   - x -> bf16 once; gather aggregation reads bf16 (halves gather bytes)
//   - GEMMs via mfma_f32_16x16x32_bf16 with XOR-swizzled LDS tiles
//   - h1 stored bf16 (halves layer-2 gather); logits fp32 -> log_softmax
// ---------------------------------------------------------------------------

constexpr int D_IN  = 128;
constexpr int HID   = 256;
constexpr int OUT_D = 64;
constexpr int SIZE1 = 25000;
constexpr int SIZE2 = 5000;

using bf16x8 = __attribute__((ext_vector_type(8))) short;  // MFMA A/B frag
using f32x4  = __attribute__((ext_vector_type(4))) float;  // MFMA C/D frag

__device__ inline unsigned short f32_to_bf16_rne(float f) {
    unsigned u = __builtin_bit_cast(unsigned, f);
    u = (u + 0x7fffu + ((u >> 16) & 1u)) >> 16;
    return (unsigned short)u;
}
__device__ inline float bf16_lo(unsigned u) {  // low ushort -> f32
    return __builtin_bit_cast(float, u << 16);
}
__device__ inline float bf16_hi(unsigned u) {  // high ushort -> f32
    return __builtin_bit_cast(float, u & 0xffff0000u);
}
__device__ inline unsigned pack_bf16(float lo, float hi) {
    return (unsigned)f32_to_bf16_rne(lo) | ((unsigned)f32_to_bf16_rne(hi) << 16);
}

// ---------------------------------------------------------------------------
// Convert x (fp32) -> bf16, vectorized: float4 in, uint2 (4x bf16) out.
// ---------------------------------------------------------------------------
__global__ void convert_x_kernel(const float* __restrict__ x,
                                 unsigned* __restrict__ xb, long n4) {
    long i = (long)blockIdx.x * blockDim.x + threadIdx.x;
    if (i >= n4) return;
    float4 v = reinterpret_cast<const float4*>(x)[i];
    uint2 o;
    o.x = pack_bf16(v.x, v.y);
    o.y = pack_bf16(v.z, v.w);
    reinterpret_cast<uint2*>(xb)[i] = o;
}

// ---------------------------------------------------------------------------
// Build transposed bf16 weights:
//   Wt1[n][k] (n<256, k<256): k<128 ? Wself1[k][n] : Wneigh1[k-128][n]
//   Wt2[n][k] (n<64,  k<512): k<256 ? Wself2[k][n] : Wneigh2[k-256][n]
// ---------------------------------------------------------------------------
__global__ void convert_w_kernel(const float* __restrict__ Ws1,
                                 const float* __restrict__ Wn1,
                                 const float* __restrict__ Ws2,
                                 const float* __restrict__ Wn2,
                                 unsigned short* __restrict__ Wt1,
                                 unsigned short* __restrict__ Wt2) {
    int i = blockIdx.x * blockDim.x + threadIdx.x;
    if (i < HID * (2 * D_IN)) {               // 256 * 256
        int n = i >> 8, k = i & 255;
        float v = (k < D_IN) ? Ws1[k * HID + n] : Wn1[(k - D_IN) * HID + n];
        Wt1[i] = f32_to_bf16_rne(v);
    } else {
        int j = i - HID * (2 * D_IN);
        if (j >= OUT_D * (2 * HID)) return;   // 64 * 512
        int n = j >> 9, k = j & 511;
        float v = (k < HID) ? Ws2[k * OUT_D + n] : Wn2[(k - HID) * OUT_D + n];
        Wt2[j] = f32_to_bf16_rne(v);
    }
}

// ---------------------------------------------------------------------------
// CSR build: histogram -> single-block scan -> slot fill
// ---------------------------------------------------------------------------
__global__ void hist_kernel(const int* __restrict__ dst, int* __restrict__ counts,
                            int E) {
    int e = blockIdx.x * blockDim.x + threadIdx.x;
    if (e < E) atomicAdd(&counts[dst[e]], 1);
}

__global__ void scan_kernel(const int* __restrict__ counts,
                            int* __restrict__ offsets, int n) {
    __shared__ int part[1024];
    const int tid = threadIdx.x;
    const int chunk = (n + 1023) / 1024;
    const int beg = tid * chunk;
    int sum = 0;
    for (int i = 0; i < chunk; ++i) {
        int idx = beg + i;
        if (idx < n) sum += counts[idx];
    }
    const int own = sum;
    part[tid] = sum;
    __syncthreads();
    for (int off = 1; off < 1024; off <<= 1) {
        int v = (tid >= off) ? part[tid - off] : 0;
        __syncthreads();
        part[tid] += v;
        __syncthreads();
    }
    if (tid == 0) offsets[n] = part[1023];
    int run = part[tid] - own;
    for (int i = 0; i < chunk; ++i) {
        int idx = beg + i;
        if (idx < n) {
            offsets[idx] = run;
            run += counts[idx];
        }
    }
}

__global__ void fill_kernel(const int* __restrict__ src, const int* __restrict__ dst,
                            const int* __restrict__ offsets, int* __restrict__ cursor,
                            int* __restrict__ csr, int E) {
    int e = blockIdx.x * blockDim.x + threadIdx.x;
    if (e >= E) return;
    int d = dst[e];
    int pos = offsets[d] + atomicAdd(&cursor[d], 1);
    csr[pos] = src[e];
}

// ---------------------------------------------------------------------------
// Pull-mode mean aggregation, bf16 in / bf16 out, fp32 accumulate.
// One wave per dst node; lane owns UPL uints (= 2*UPL bf16 columns).
// ---------------------------------------------------------------------------
template <int UPL>
__global__ void agg_pull_bf16(const unsigned* __restrict__ Xu,
                              const int* __restrict__ csr,
                              const int* __restrict__ offsets,
                              unsigned* __restrict__ meanu, int ndst) {
    constexpr int DU = UPL * 64;  // uints per row
    const int wid = threadIdx.x >> 6;
    const int lane = threadIdx.x & 63;
    const int d = blockIdx.x * 4 + wid;
    if (d >= ndst) return;
    const int beg = offsets[d];
    const int end = offsets[d + 1];
    float accl[UPL], acch[UPL];
#pragma unroll
    for (int q = 0; q < UPL; ++q) accl[q] = acch[q] = 0.0f;
    int e = beg;
    for (; e + 1 < end; e += 2) {
        long s0 = csr[e];
        long s1 = csr[e + 1];
#pragma unroll
        for (int q = 0; q < UPL; ++q) {
            unsigned u0 = Xu[s0 * DU + q * 64 + lane];
            unsigned u1 = Xu[s1 * DU + q * 64 + lane];
            accl[q] += bf16_lo(u0) + bf16_lo(u1);
            acch[q] += bf16_hi(u0) + bf16_hi(u1);
        }
    }
    if (e < end) {
        long s0 = csr[e];
#pragma unroll
        for (int q = 0; q < UPL; ++q) {
            unsigned u0 = Xu[s0 * DU + q * 64 + lane];
            accl[q] += bf16_lo(u0);
            acch[q] += bf16_hi(u0);
        }
    }
    const float inv = 1.0f / (float)max(end - beg, 1);
#pragma unroll
    for (int q = 0; q < UPL; ++q)
        meanu[(long)d * DU + q * 64 + lane] = pack_bf16(accl[q] * inv, acch[q] * inv);
}

// ---------------------------------------------------------------------------
// Fused SAGE GEMM via MFMA (bf16 in, fp32 acc).
//   C[i][n] = act( Aself[i][0:KPH]@Wt[n][0:KPH]
//                + Amean[i][0:KPH]@Wt[n][KPH:2*KPH] + bias[n] )
// Aself/Amean: [M][KPH] bf16 row-major. Wt: [N][2*KPH] bf16 (pre-transposed).
// Block: 256 threads = 4 waves (2x2), 64x64 tile, wave = 32x32 (2x2 frags).
// LDS tiles XOR-swizzled (element idx ^= (row&7)<<3) for conflict-free b128.
// ---------------------------------------------------------------------------
template <int KPH, bool RELU, bool OUT_BF16>
__global__ __launch_bounds__(256) void sage_gemm_mfma(
    const unsigned short* __restrict__ Aself,
    const unsigned short* __restrict__ Amean,
    const unsigned short* __restrict__ Wt,
    const float* __restrict__ bias,
    void* __restrict__ Cout, int M, int N) {
    constexpr int BM = 64, BN = 64;
    constexpr int ITERS = (BM * KPH) / (256 * 8);
    __shared__ unsigned short As[BM * KPH];
    __shared__ unsigned short Bs[BN * KPH];

    const int tid = threadIdx.x;
    const int wid = tid >> 6;
    const int lane = tid & 63;
    const int wm = wid >> 1, wn = wid & 1;
    const int rowBase = blockIdx.x * BM;
    const int colBase = blockIdx.y * BN;

    f32x4 acc[2][2];
#pragma unroll
    for (int a = 0; a < 2; ++a)
#pragma unroll
        for (int b = 0; b < 2; ++b)
#pragma unroll
            for (int j = 0; j < 4; ++j) acc[a][b][j] = 0.0f;

#pragma unroll
    for (int p = 0; p < 2; ++p) {
        const unsigned short* __restrict__ A = p ? Amean : Aself;
        __syncthreads();
        // stage A tile (rows rowBase..+63, k 0..KPH)
#pragma unroll
        for (int it = 0; it < ITERS; ++it) {
            int flat = (it * 256 + tid) * 8;
            int r = flat / KPH, kc = flat % KPH;
            int gr = rowBase + r;
            if (gr >= M) gr = M - 1;
            uint4 v = *reinterpret_cast<const uint4*>(&A[(long)gr * KPH + kc]);
            int idx = (r * KPH + kc) ^ ((r & 7) << 3);
            *reinterpret_cast<uint4*>(&As[idx]) = v;
        }
        // stage B tile (Wt rows colBase..+63, k p*KPH..+KPH)
#pragma unroll
        for (int it = 0; it < ITERS; ++it) {
            int flat = (it * 256 + tid) * 8;
            int r = flat / KPH, kc = flat % KPH;
            uint4 v = *reinterpret_cast<const uint4*>(
                &Wt[(long)(colBase + r) * (2 * KPH) + p * KPH + kc]);
            int idx = (r * KPH + kc) ^ ((r & 7) << 3);
            *reinterpret_cast<uint4*>(&Bs[idx]) = v;
        }
        __syncthreads();
#pragma unroll
        for (int kk = 0; kk < KPH / 32; ++kk) {
            bf16x8 a[2], b[2];
            const int kb = kk * 32 + 8 * (lane >> 4);
#pragma unroll
            for (int f = 0; f < 2; ++f) {
                int r = wm * 32 + f * 16 + (lane & 15);
                int ia = (r * KPH + kb) ^ ((r & 7) << 3);
                a[f] = *reinterpret_cast<const bf16x8*>(&As[ia]);
                int rn = wn * 32 + f * 16 + (lane & 15);
                int ib = (rn * KPH + kb) ^ ((rn & 7) << 3);
                b[f] = *reinterpret_cast<const bf16x8*>(&Bs[ib]);
            }
#pragma unroll
            for (int fm = 0; fm < 2; ++fm)
#pragma unroll
                for (int fn = 0; fn < 2; ++fn)
                    acc[fm][fn] = __builtin_amdgcn_mfma_f32_16x16x32_bf16(
                        a[fm], b[fn], acc[fm][fn], 0, 0, 0);
        }
    }

    // epilogue: D[row][col] with col=lane&15, row=4*(lane>>4)+j
#pragma unroll
    for (int fm = 0; fm < 2; ++fm) {
#pragma unroll
        for (int fn = 0; fn < 2; ++fn) {
            int gc = colBase + wn * 32 + fn * 16 + (lane & 15);
            float bv = bias[gc];
#pragma unroll
            for (int j = 0; j < 4; ++j) {
                int gr = rowBase + wm * 32 + fm * 16 + 4 * (lane >> 4) + j;
                if (gr < M) {
                    float v = acc[fm][fn][j] + bv;
                    if (RELU) v = fmaxf(v, 0.0f);
                    if (OUT_BF16)
                        ((unsigned short*)Cout)[(long)gr * N + gc] = f32_to_bf16_rne(v);
                    else
                        ((float*)Cout)[(long)gr * N + gc] = v;
                }
            }
        }
    }
}

// ---------------------------------------------------------------------------
// In-place log_softmax over rows of 64. One wave per row.
// ---------------------------------------------------------------------------
__global__ void log_softmax_kernel(float* __restrict__ C, int M) {
    int row = blockIdx.x * 4 + (threadIdx.x >> 6);
    int lane = threadIdx.x & 63;
    if (row >= M) return;
    float v = C[(long)row * OUT_D + lane];
    float m = v;
#pragma unroll
    for (int o = 32; o; o >>= 1) m = fmaxf(m, __shfl_xor(m, o));
    float ex = __expf(v - m);
    float s = ex;
#pragma unroll
    for (int o = 32; o; o >>= 1) s += __shfl_xor(s, o);
    C[(long)row * OUT_D + lane] = v - m - __logf(s);
}

// ---------------------------------------------------------------------------

extern "C" void kernel_launch(void* const* d_in, const int* in_sizes, int n_in,
                              void* d_out, int out_size, void* d_ws, size_t ws_size,
                              hipStream_t stream) {
    const float* x       = (const float*)d_in[0];
    const float* Wself1  = (const float*)d_in[1];
    const float* Wneigh1 = (const float*)d_in[2];
    const float* b1      = (const float*)d_in[3];
    const float* Wself2  = (const float*)d_in[4];
    const float* Wneigh2 = (const float*)d_in[5];
    const float* b2      = (const float*)d_in[6];
    const int* es1 = (const int*)d_in[7];
    const int* ed1 = (const int*)d_in[8];
    const int* es2 = (const int*)d_in[9];
    const int* ed2 = (const int*)d_in[10];
    const int E1 = in_sizes[7];
    const int E2 = in_sizes[9];
    const long NSRC = in_sizes[0] / D_IN;  // 100000

    // ---- workspace layout ----
    int* counts1  = (int*)d_ws;                      // SIZE1
    int* cursor1  = counts1 + SIZE1;                 // SIZE1
    int* counts2  = cursor1 + SIZE1;                 // SIZE2
    int* cursor2  = counts2 + SIZE2;                 // SIZE2
    int* offsets1 = cursor2 + SIZE2;                 // SIZE1+1
    int* offsets2 = offsets1 + SIZE1 + 1;            // SIZE2+1
    int* csr1     = offsets2 + SIZE2 + 1;            // E1
    int* csr2     = csr1 + E1;                       // E2
    // pad to 16B and switch to bf16 storage
    size_t int_elems = (size_t)(2 * SIZE1 + 2 * SIZE2 + SIZE1 + 1 + SIZE2 + 1) + E1 + E2;
    int_elems = (int_elems + 3) & ~(size_t)3;
    unsigned short* xb    = (unsigned short*)((int*)d_ws + int_elems);  // NSRC*128
    unsigned short* Wt1   = xb + NSRC * D_IN;                 // 256*256
    unsigned short* Wt2   = Wt1 + (size_t)HID * (2 * D_IN);   // 64*512
    unsigned short* mean1 = Wt2 + (size_t)OUT_D * (2 * HID);  // SIZE1*128
    unsigned short* mean2 = mean1 + (size_t)SIZE1 * D_IN;     // SIZE2*256
    unsigned short* h1    = mean2 + (size_t)SIZE2 * HID;      // SIZE1*256

    hipMemsetAsync(d_ws, 0, (2 * SIZE1 + 2 * SIZE2) * sizeof(int), stream);

    // ---- conversions ----
    {
        long n4 = NSRC * D_IN / 4;
        convert_x_kernel<<<(int)((n4 + 255) / 256), 256, 0, stream>>>(
            x, (unsigned*)xb, n4);
        int wtot = HID * (2 * D_IN) + OUT_D * (2 * HID);
        convert_w_kernel<<<(wtot + 255) / 256, 256, 0, stream>>>(
            Wself1, Wneigh1, Wself2, Wneigh2, Wt1, Wt2);
    }

    // ---- layer 1: CSR + pull-mean + GEMM ----
    hist_kernel<<<(E1 + 255) / 256, 256, 0, stream>>>(ed1, counts1, E1);
    scan_kernel<<<1, 1024, 0, stream>>>(counts1, offsets1, SIZE1);
    fill_kernel<<<(E1 + 255) / 256, 256, 0, stream>>>(es1, ed1, offsets1, cursor1,
                                                      csr1, E1);
    agg_pull_bf16<1><<<(SIZE1 + 3) / 4, 256, 0, stream>>>(
        (const unsigned*)xb, csr1, offsets1, (unsigned*)mean1, SIZE1);
    {
        dim3 grid((SIZE1 + 63) / 64, HID / 64);
        sage_gemm_mfma<D_IN, true, true><<<grid, 256, 0, stream>>>(
            xb, mean1, Wt1, b1, h1, SIZE1, HID);
    }

    // ---- layer 2: CSR + pull-mean + GEMM ----
    hist_kernel<<<(E2 + 255) / 256, 256, 0, stream>>>(ed2, counts2, E2);
    scan_kernel<<<1, 1024, 0, stream>>>(counts2, offsets2, SIZE2);
    fill_kernel<<<(E2 + 255) / 256, 256, 0, stream>>>(es2, ed2, offsets2, cursor2,
                                                      csr2, E2);
    agg_pull_bf16<2><<<(SIZE2 + 3) / 4, 256, 0, stream>>>(
        (const unsigned*)h1, csr2, offsets2, (unsigned*)mean2, SIZE2);
    {
        dim3 grid((SIZE2 + 63) / 64, OUT_D / 64);
        sage_gemm_mfma<HID, false, false><<<grid, 256, 0, stream>>>(
            h1, mean2, Wt2, b2, d_out, SIZE2, OUT_D);
    }

    // ---- log_softmax in place on d_out ----
    log_softmax_kernel<<<(SIZE2 + 3) / 4, 256, 0, stream>>>((float*)d_out, SIZE2);
}

// Round 4
// 238.856 us; speedup vs baseline: 8.5724x; 1.1471x over previous
//
#include <hip/hip_runtime.h>

// ---------------------------------------------------------------------------
// SAGE_DGL: 2-layer GraphSAGE (mean agg) forward on MI355X.
// Round 4:
//   - agg: 16 lanes/row x 4 edge-groups, uint4 (16B/lane) loads, 2-edge ILP,
//     shfl_xor cross-group reduce  (was: 4B/lane, latency-bound)
//   - fuse independent kernels: {convert_x, convert_w, hist1, hist2},
//     {scan1, scan2}, {fill1, fill2} to overlap latency inside one dispatch
//   - fill: nontemporal csr stores
// ---------------------------------------------------------------------------

constexpr int D_IN  = 128;
constexpr int HID   = 256;
constexpr int OUT_D = 64;
constexpr int SIZE1 = 25000;
constexpr int SIZE2 = 5000;

using bf16x8 = __attribute__((ext_vector_type(8))) short;  // MFMA A/B frag
using f32x4  = __attribute__((ext_vector_type(4))) float;  // MFMA C/D frag

__device__ inline unsigned short f32_to_bf16_rne(float f) {
    unsigned u = __builtin_bit_cast(unsigned, f);
    u = (u + 0x7fffu + ((u >> 16) & 1u)) >> 16;
    return (unsigned short)u;
}
__device__ inline float bf16_lo(unsigned u) {
    return __builtin_bit_cast(float, u << 16);
}
__device__ inline float bf16_hi(unsigned u) {
    return __builtin_bit_cast(float, u & 0xffff0000u);
}
__device__ inline unsigned pack_bf16(float lo, float hi) {
    return (unsigned)f32_to_bf16_rne(lo) | ((unsigned)f32_to_bf16_rne(hi) << 16);
}
__device__ inline void add8(float* a, uint4 v) {
    a[0] += bf16_lo(v.x); a[1] += bf16_hi(v.x);
    a[2] += bf16_lo(v.y); a[3] += bf16_hi(v.y);
    a[4] += bf16_lo(v.z); a[5] += bf16_hi(v.z);
    a[6] += bf16_lo(v.w); a[7] += bf16_hi(v.w);
}

// ---------------------------------------------------------------------------
// Fused pre-pass: convert x->bf16 | build Wt1/Wt2 (bf16, transposed,
// self||neigh concatenated along K) | hist(dst1) | hist(dst2).
// Block role by blockIdx range (all parts independent).
// ---------------------------------------------------------------------------
__global__ void pre_kernel(const float* __restrict__ x, unsigned* __restrict__ xb,
                           long n4,
                           const float* __restrict__ Ws1, const float* __restrict__ Wn1,
                           const float* __restrict__ Ws2, const float* __restrict__ Wn2,
                           unsigned short* __restrict__ Wt1,
                           unsigned short* __restrict__ Wt2,
                           const int* __restrict__ ed1, int* __restrict__ counts1, int E1,
                           const int* __restrict__ ed2, int* __restrict__ counts2, int E2,
                           int c0, int c1, int c2) {
    const int b = blockIdx.x;
    const int tid = threadIdx.x;
    if (b < c0) {                      // convert x -> bf16
        long i = (long)b * 256 + tid;
        if (i < n4) {
            float4 v = reinterpret_cast<const float4*>(x)[i];
            uint2 o;
            o.x = pack_bf16(v.x, v.y);
            o.y = pack_bf16(v.z, v.w);
            reinterpret_cast<uint2*>(xb)[i] = o;
        }
    } else if (b < c1) {               // convert weights
        int i = (b - c0) * 256 + tid;
        if (i < HID * (2 * D_IN)) {    // Wt1: 256 x 256
            int n = i >> 8, k = i & 255;
            float v = (k < D_IN) ? Ws1[k * HID + n] : Wn1[(k - D_IN) * HID + n];
            Wt1[i] = f32_to_bf16_rne(v);
        } else {
            int j = i - HID * (2 * D_IN);
            if (j < OUT_D * (2 * HID)) {  // Wt2: 64 x 512
                int n = j >> 9, k = j & 511;
                float v = (k < HID) ? Ws2[k * OUT_D + n] : Wn2[(k - HID) * OUT_D + n];
                Wt2[j] = f32_to_bf16_rne(v);
            }
        }
    } else if (b < c2) {               // hist layer 1
        int e = (b - c1) * 256 + tid;
        if (e < E1) atomicAdd(&counts1[ed1[e]], 1);
    } else {                           // hist layer 2
        int e = (b - c2) * 256 + tid;
        if (e < E2) atomicAdd(&counts2[ed2[e]], 1);
    }
}

// ---------------------------------------------------------------------------
// Fused exclusive scans: block 0 -> layer 1, block 1 -> layer 2.
// ---------------------------------------------------------------------------
__device__ void scan_body(const int* __restrict__ counts,
                          int* __restrict__ offsets, int n) {
    __shared__ int part[1024];
    const int tid = threadIdx.x;
    const int chunk = (n + 1023) / 1024;
    const int beg = tid * chunk;
    int sum = 0;
    for (int i = 0; i < chunk; ++i) {
        int idx = beg + i;
        if (idx < n) sum += counts[idx];
    }
    const int own = sum;
    part[tid] = sum;
    __syncthreads();
    for (int off = 1; off < 1024; off <<= 1) {
        int v = (tid >= off) ? part[tid - off] : 0;
        __syncthreads();
        part[tid] += v;
        __syncthreads();
    }
    if (tid == 0) offsets[n] = part[1023];
    int run = part[tid] - own;
    for (int i = 0; i < chunk; ++i) {
        int idx = beg + i;
        if (idx < n) {
            offsets[idx] = run;
            run += counts[idx];
        }
    }
}

__global__ void scan_fused(const int* __restrict__ c1, int* __restrict__ o1, int n1,
                           const int* __restrict__ c2, int* __restrict__ o2, int n2) {
    if (blockIdx.x == 0) scan_body(c1, o1, n1);
    else scan_body(c2, o2, n2);
}

// ---------------------------------------------------------------------------
// Fused CSR fill (both layers), nontemporal scattered stores.
// ---------------------------------------------------------------------------
__global__ void fill_fused(const int* __restrict__ es1, const int* __restrict__ ed1,
                           const int* __restrict__ off1, int* __restrict__ cur1,
                           int* __restrict__ csr1, int E1, int f1,
                           const int* __restrict__ es2, const int* __restrict__ ed2,
                           const int* __restrict__ off2, int* __restrict__ cur2,
                           int* __restrict__ csr2, int E2) {
    const int b = blockIdx.x;
    const int tid = threadIdx.x;
    if (b < f1) {
        int e = b * 256 + tid;
        if (e < E1) {
            int d = ed1[e];
            int pos = off1[d] + atomicAdd(&cur1[d], 1);
            __builtin_nontemporal_store(es1[e], &csr1[pos]);
        }
    } else {
        int e = (b - f1) * 256 + tid;
        if (e < E2) {
            int d = ed2[e];
            int pos = off2[d] + atomicAdd(&cur2[d], 1);
            __builtin_nontemporal_store(es2[e], &csr2[pos]);
        }
    }
}

// ---------------------------------------------------------------------------
// Pull-mode mean aggregation (bf16 in/out, fp32 accumulate).
// Wave per dst node. 4 groups of 16 lanes; group g handles edges e+g (and
// e+4+g), lane loads uint4 (16B) of the row. Cross-group shfl reduce.
// QPL = uint4 per lane per row (D=128 -> 1, D=256 -> 2).
// ---------------------------------------------------------------------------
template <int QPL>
__global__ void agg_pull2(const uint4* __restrict__ X4,
                          const int* __restrict__ csr,
                          const int* __restrict__ offsets,
                          uint4* __restrict__ mean4, int ndst) {
    constexpr int R4 = QPL * 16;  // uint4 per row
    const int wid = threadIdx.x >> 6;
    const int lane = threadIdx.x & 63;
    const int d = blockIdx.x * 4 + wid;
    if (d >= ndst) return;
    const int beg = offsets[d];
    const int end = offsets[d + 1];
    const int g = lane >> 4;
    const int c = lane & 15;

    float acc[QPL][8];
#pragma unroll
    for (int q = 0; q < QPL; ++q)
#pragma unroll
        for (int j = 0; j < 8; ++j) acc[q][j] = 0.0f;

    for (int e = beg + g; e < end; e += 8) {
        long sA = csr[e];
#pragma unroll
        for (int q = 0; q < QPL; ++q) {
            uint4 v = X4[sA * R4 + q * 16 + c];
            add8(acc[q], v);
        }
        int e2 = e + 4;
        if (e2 < end) {
            long sB = csr[e2];
#pragma unroll
            for (int q = 0; q < QPL; ++q) {
                uint4 v = X4[sB * R4 + q * 16 + c];
                add8(acc[q], v);
            }
        }
    }
    // reduce across the 4 groups (lanes l, l^16, l^32, l^48)
#pragma unroll
    for (int q = 0; q < QPL; ++q)
#pragma unroll
        for (int j = 0; j < 8; ++j) {
            acc[q][j] += __shfl_xor(acc[q][j], 16);
            acc[q][j] += __shfl_xor(acc[q][j], 32);
        }
    if (g == 0) {
        const float inv = 1.0f / (float)max(end - beg, 1);
#pragma unroll
        for (int q = 0; q < QPL; ++q) {
            uint4 o;
            o.x = pack_bf16(acc[q][0] * inv, acc[q][1] * inv);
            o.y = pack_bf16(acc[q][2] * inv, acc[q][3] * inv);
            o.z = pack_bf16(acc[q][4] * inv, acc[q][5] * inv);
            o.w = pack_bf16(acc[q][6] * inv, acc[q][7] * inv);
            mean4[(long)d * R4 + q * 16 + c] = o;
        }
    }
}

// ---------------------------------------------------------------------------
// Fused SAGE GEMM via MFMA (bf16 in, fp32 acc). See round 3 notes.
// ---------------------------------------------------------------------------
template <int KPH, bool RELU, bool OUT_BF16>
__global__ __launch_bounds__(256) void sage_gemm_mfma(
    const unsigned short* __restrict__ Aself,
    const unsigned short* __restrict__ Amean,
    const unsigned short* __restrict__ Wt,
    const float* __restrict__ bias,
    void* __restrict__ Cout, int M, int N) {
    constexpr int BM = 64, BN = 64;
    constexpr int ITERS = (BM * KPH) / (256 * 8);
    __shared__ unsigned short As[BM * KPH];
    __shared__ unsigned short Bs[BN * KPH];

    const int tid = threadIdx.x;
    const int wid = tid >> 6;
    const int lane = tid & 63;
    const int wm = wid >> 1, wn = wid & 1;
    const int rowBase = blockIdx.x * BM;
    const int colBase = blockIdx.y * BN;

    f32x4 acc[2][2];
#pragma unroll
    for (int a = 0; a < 2; ++a)
#pragma unroll
        for (int b = 0; b < 2; ++b)
#pragma unroll
            for (int j = 0; j < 4; ++j) acc[a][b][j] = 0.0f;

#pragma unroll
    for (int p = 0; p < 2; ++p) {
        const unsigned short* __restrict__ A = p ? Amean : Aself;
        __syncthreads();
#pragma unroll
        for (int it = 0; it < ITERS; ++it) {
            int flat = (it * 256 + tid) * 8;
            int r = flat / KPH, kc = flat % KPH;
            int gr = rowBase + r;
            if (gr >= M) gr = M - 1;
            uint4 v = *reinterpret_cast<const uint4*>(&A[(long)gr * KPH + kc]);
            int idx = (r * KPH + kc) ^ ((r & 7) << 3);
            *reinterpret_cast<uint4*>(&As[idx]) = v;
        }
#pragma unroll
        for (int it = 0; it < ITERS; ++it) {
            int flat = (it * 256 + tid) * 8;
            int r = flat / KPH, kc = flat % KPH;
            uint4 v = *reinterpret_cast<const uint4*>(
                &Wt[(long)(colBase + r) * (2 * KPH) + p * KPH + kc]);
            int idx = (r * KPH + kc) ^ ((r & 7) << 3);
            *reinterpret_cast<uint4*>(&Bs[idx]) = v;
        }
        __syncthreads();
#pragma unroll
        for (int kk = 0; kk < KPH / 32; ++kk) {
            bf16x8 a[2], b[2];
            const int kb = kk * 32 + 8 * (lane >> 4);
#pragma unroll
            for (int f = 0; f < 2; ++f) {
                int r = wm * 32 + f * 16 + (lane & 15);
                int ia = (r * KPH + kb) ^ ((r & 7) << 3);
                a[f] = *reinterpret_cast<const bf16x8*>(&As[ia]);
                int rn = wn * 32 + f * 16 + (lane & 15);
                int ib = (rn * KPH + kb) ^ ((rn & 7) << 3);
                b[f] = *reinterpret_cast<const bf16x8*>(&Bs[ib]);
            }
#pragma unroll
            for (int fm = 0; fm < 2; ++fm)
#pragma unroll
                for (int fn = 0; fn < 2; ++fn)
                    acc[fm][fn] = __builtin_amdgcn_mfma_f32_16x16x32_bf16(
                        a[fm], b[fn], acc[fm][fn], 0, 0, 0);
        }
    }

#pragma unroll
    for (int fm = 0; fm < 2; ++fm) {
#pragma unroll
        for (int fn = 0; fn < 2; ++fn) {
            int gc = colBase + wn * 32 + fn * 16 + (lane & 15);
            float bv = bias[gc];
#pragma unroll
            for (int j = 0; j < 4; ++j) {
                int gr = rowBase + wm * 32 + fm * 16 + 4 * (lane >> 4) + j;
                if (gr < M) {
                    float v = acc[fm][fn][j] + bv;
                    if (RELU) v = fmaxf(v, 0.0f);
                    if (OUT_BF16)
                        ((unsigned short*)Cout)[(long)gr * N + gc] = f32_to_bf16_rne(v);
                    else
                        ((float*)Cout)[(long)gr * N + gc] = v;
                }
            }
        }
    }
}

// ---------------------------------------------------------------------------
// In-place log_softmax over rows of 64. One wave per row.
// ---------------------------------------------------------------------------
__global__ void log_softmax_kernel(float* __restrict__ C, int M) {
    int row = blockIdx.x * 4 + (threadIdx.x >> 6);
    int lane = threadIdx.x & 63;
    if (row >= M) return;
    float v = C[(long)row * OUT_D + lane];
    float m = v;
#pragma unroll
    for (int o = 32; o; o >>= 1) m = fmaxf(m, __shfl_xor(m, o));
    float ex = __expf(v - m);
    float s = ex;
#pragma unroll
    for (int o = 32; o; o >>= 1) s += __shfl_xor(s, o);
    C[(long)row * OUT_D + lane] = v - m - __logf(s);
}

// ---------------------------------------------------------------------------

extern "C" void kernel_launch(void* const* d_in, const int* in_sizes, int n_in,
                              void* d_out, int out_size, void* d_ws, size_t ws_size,
                              hipStream_t stream) {
    const float* x       = (const float*)d_in[0];
    const float* Wself1  = (const float*)d_in[1];
    const float* Wneigh1 = (const float*)d_in[2];
    const float* b1      = (const float*)d_in[3];
    const float* Wself2  = (const float*)d_in[4];
    const float* Wneigh2 = (const float*)d_in[5];
    const float* b2      = (const float*)d_in[6];
    const int* es1 = (const int*)d_in[7];
    const int* ed1 = (const int*)d_in[8];
    const int* es2 = (const int*)d_in[9];
    const int* ed2 = (const int*)d_in[10];
    const int E1 = in_sizes[7];
    const int E2 = in_sizes[9];
    const long NSRC = in_sizes[0] / D_IN;  // 100000

    // ---- workspace layout ----
    int* counts1  = (int*)d_ws;                      // SIZE1
    int* cursor1  = counts1 + SIZE1;                 // SIZE1
    int* counts2  = cursor1 + SIZE1;                 // SIZE2
    int* cursor2  = counts2 + SIZE2;                 // SIZE2
    int* offsets1 = cursor2 + SIZE2;                 // SIZE1+1
    int* offsets2 = offsets1 + SIZE1 + 1;            // SIZE2+1
    int* csr1     = offsets2 + SIZE2 + 1;            // E1
    int* csr2     = csr1 + E1;                       // E2
    size_t int_elems = (size_t)(2 * SIZE1 + 2 * SIZE2 + SIZE1 + 1 + SIZE2 + 1) + E1 + E2;
    int_elems = (int_elems + 3) & ~(size_t)3;        // 16B align
    unsigned short* xb    = (unsigned short*)((int*)d_ws + int_elems);  // NSRC*128
    unsigned short* Wt1   = xb + NSRC * D_IN;                 // 256*256
    unsigned short* Wt2   = Wt1 + (size_t)HID * (2 * D_IN);   // 64*512
    unsigned short* mean1 = Wt2 + (size_t)OUT_D * (2 * HID);  // SIZE1*128
    unsigned short* mean2 = mean1 + (size_t)SIZE1 * D_IN;     // SIZE2*256
    unsigned short* h1    = mean2 + (size_t)SIZE2 * HID;      // SIZE1*256

    hipMemsetAsync(d_ws, 0, (2 * SIZE1 + 2 * SIZE2) * sizeof(int), stream);

    // ---- fused pre-pass: conversions + histograms ----
    const long n4 = NSRC * D_IN / 4;
    const int nb_cx = (int)((n4 + 255) / 256);
    const int nb_cw = (HID * (2 * D_IN) + OUT_D * (2 * HID) + 255) / 256;
    const int nb_h1 = (E1 + 255) / 256;
    const int nb_h2 = (E2 + 255) / 256;
    const int c0 = nb_cx, c1 = c0 + nb_cw, c2 = c1 + nb_h1, c3 = c2 + nb_h2;
    pre_kernel<<<c3, 256, 0, stream>>>(x, (unsigned*)xb, n4,
                                       Wself1, Wneigh1, Wself2, Wneigh2, Wt1, Wt2,
                                       ed1, counts1, E1, ed2, counts2, E2,
                                       c0, c1, c2);

    // ---- fused scans ----
    scan_fused<<<2, 1024, 0, stream>>>(counts1, offsets1, SIZE1,
                                       counts2, offsets2, SIZE2);

    // ---- fused CSR fills ----
    fill_fused<<<nb_h1 + nb_h2, 256, 0, stream>>>(
        es1, ed1, offsets1, cursor1, csr1, E1, nb_h1,
        es2, ed2, offsets2, cursor2, csr2, E2);

    // ---- layer 1: pull-mean + GEMM ----
    agg_pull2<1><<<(SIZE1 + 3) / 4, 256, 0, stream>>>(
        (const uint4*)xb, csr1, offsets1, (uint4*)mean1, SIZE1);
    {
        dim3 grid((SIZE1 + 63) / 64, HID / 64);
        sage_gemm_mfma<D_IN, true, true><<<grid, 256, 0, stream>>>(
            xb, mean1, Wt1, b1, h1, SIZE1, HID);
    }

    // ---- layer 2: pull-mean + GEMM ----
    agg_pull2<2><<<(SIZE2 + 3) / 4, 256, 0, stream>>>(
        (const uint4*)h1, csr2, offsets2, (uint4*)mean2, SIZE2);
    {
        dim3 grid((SIZE2 + 63) / 64, OUT_D / 64);
        sage_gemm_mfma<HID, false, false><<<grid, 256, 0, stream>>>(
            h1, mean2, Wt2, b2, d_out, SIZE2, OUT_D);
    }

    // ---- log_softmax in place on d_out ----
    log_softmax_kernel<<<(SIZE2 + 3) / 4, 256, 0, stream>>>((float*)d_out, SIZE2);
}